// Round 1
// baseline (223.758 us; speedup 1.0000x reference)
//
#include <hip/hip_runtime.h>
#include <math.h>

// mat2twist: in = B x 3 x 3 fp32 rotation matrices, out = B x 3 axis-angle.
// Memory-bound (201 MB traffic). Each thread handles 4 matrices so that both
// loads (9 x float4) and stores (3 x float4) are 16B/lane fully coalesced.

__global__ __launch_bounds__(256) void mat2twist_kernel(
    const float4* __restrict__ in4,
    float4* __restrict__ out4,
    int n_quads,          // n_mat / 4
    const float* __restrict__ in_s,  // scalar view for tail
    float* __restrict__ out_s,
    int n_mat) {

    int idx = blockIdx.x * blockDim.x + threadIdx.x;
    int stride = gridDim.x * blockDim.x;

    for (int q = idx; q < n_quads; q += stride) {
        const float4* p = in4 + (size_t)q * 9;
        float m[36];
#pragma unroll
        for (int i = 0; i < 9; ++i) {
            float4 v = p[i];
            m[4 * i + 0] = v.x;
            m[4 * i + 1] = v.y;
            m[4 * i + 2] = v.z;
            m[4 * i + 3] = v.w;
        }
        float r[12];
#pragma unroll
        for (int j = 0; j < 4; ++j) {
            const float* a = m + 9 * j;   // matrix j, row-major 3x3
            float tr = a[0] + a[4] + a[8];
            float c  = 0.5f * (tr - 1.0f);
            float ang = acosf(c);
            // sin(acos(c)) = sqrt(1 - c^2); theta in [0.1, pi-0.1] -> safe
            float s2 = fmaxf(1.0f - c * c, 1e-30f);
            float k  = ang * 0.5f / sqrtf(s2);
            r[3 * j + 0] = k * (a[7] - a[5]);
            r[3 * j + 1] = k * (a[2] - a[6]);
            r[3 * j + 2] = k * (a[3] - a[1]);
        }
        float4* o = out4 + (size_t)q * 3;
        o[0] = make_float4(r[0], r[1], r[2],  r[3]);
        o[1] = make_float4(r[4], r[5], r[6],  r[7]);
        o[2] = make_float4(r[8], r[9], r[10], r[11]);
    }

    // Scalar tail (n_mat % 4 != 0) — not hit for B=4194304, kept for safety.
    if (idx == 0) {
        for (int i = n_quads * 4; i < n_mat; ++i) {
            const float* a = in_s + (size_t)i * 9;
            float tr = a[0] + a[4] + a[8];
            float c  = 0.5f * (tr - 1.0f);
            float ang = acosf(c);
            float s2 = fmaxf(1.0f - c * c, 1e-30f);
            float k  = ang * 0.5f / sqrtf(s2);
            out_s[3 * i + 0] = k * (a[7] - a[5]);
            out_s[3 * i + 1] = k * (a[2] - a[6]);
            out_s[3 * i + 2] = k * (a[3] - a[1]);
        }
    }
}

extern "C" void kernel_launch(void* const* d_in, const int* in_sizes, int n_in,
                              void* d_out, int out_size, void* d_ws, size_t ws_size,
                              hipStream_t stream) {
    const float* in = (const float*)d_in[0];
    float* out = (float*)d_out;
    int n_mat = in_sizes[0] / 9;
    int n_quads = n_mat / 4;

    int block = 256;
    int grid = (n_quads + block - 1) / block;
    if (grid > 4096) grid = 4096;   // grid-stride beyond this
    if (grid < 1) grid = 1;

    mat2twist_kernel<<<grid, block, 0, stream>>>(
        (const float4*)in, (float4*)out, n_quads, in, out, n_mat);
}